// Round 17
// baseline (175.503 us; speedup 1.0000x reference)
//
#include <hip/hip_runtime.h>
#include <hip/hip_bf16.h>
#include <math.h>

// CrossAttentionModule: 3D neighborhood attention (NATTEN-style clamped window)
// B=1, C=64, D=64, H=64, W=8, HEADS=8, hd=8, K=(3,3,3), dil=1.
//
// R17 = R16 + DIAGNOSTIC repetition (stats x16, qkv x8, attn x4), idempotent
// bodies with asm memory-clobbers between reps. Purpose: surface all three
// kernels' rocprof rows above the ~44us harness fill dispatches and get
// true per-kernel time = dur/rep + real VALUBusy/FETCH/Occupancy counters.
// Functional output identical to R16 (best: 45.07us).

#define PD 64
#define PH 64
#define PW 8
#define PTOT (PD*PH*PW)   // 32768
#define NC 64
#define NHEADS 8
#define HD 8
#define ATT_SCALE 0.35355339059327373f  // 1/sqrt(8)

#define REP_STATS 16
#define REP_QKV   8
#define REP_ATTN  4

// ws layout (floats)
#define WS_MR   0                        // 128 tc x {mean,rstd}
#define WS_Q16  1024                     // PTOT*64 ushorts = PTOT*32 floats
#define WS_K16  (WS_Q16 + PTOT*32)
#define WS_V16  (WS_K16 + PTOT*32)
// u16 index within a tensor: (d*64+h)*512 + head*64 + w*8 + hd

__device__ __forceinline__ void unpack8(uint4 u, float f[8]) {
  union { unsigned int i; float x; } a;
  a.i = u.x << 16;          f[0] = a.x;
  a.i = u.x & 0xffff0000u;  f[1] = a.x;
  a.i = u.y << 16;          f[2] = a.x;
  a.i = u.y & 0xffff0000u;  f[3] = a.x;
  a.i = u.z << 16;          f[4] = a.x;
  a.i = u.z & 0xffff0000u;  f[5] = a.x;
  a.i = u.w << 16;          f[6] = a.x;
  a.i = u.w & 0xffff0000u;  f[7] = a.x;
}

__device__ __forceinline__ uint4 shfl4(uint4 v, int src) {
  uint4 r;
  r.x = (unsigned)__shfl((int)v.x, src, 64);
  r.y = (unsigned)__shfl((int)v.y, src, 64);
  r.z = (unsigned)__shfl((int)v.z, src, 64);
  r.w = (unsigned)__shfl((int)v.w, src, 64);
  return r;
}

__global__ __launch_bounds__(1024) void k_stats(const float* __restrict__ skip,
                                                const float* __restrict__ up,
                                                float* __restrict__ ws) {
  int tc = blockIdx.x;                // 0..127
  const float* src = (tc < 64) ? (skip + (size_t)tc * PTOT)
                               : (up + (size_t)(tc - 64) * PTOT);
  const float4* b4 = (const float4*)src;
  __shared__ float red[32];
  for (int rep = 0; rep < REP_STATS; rep++) {
    float s1 = 0.f, s2 = 0.f;
    #pragma unroll
    for (int it = 0; it < 8; it++) {
      float4 v = b4[it * 1024 + threadIdx.x];
      s1 += v.x + v.y + v.z + v.w;
      s2 += v.x*v.x + v.y*v.y + v.z*v.z + v.w*v.w;
    }
    #pragma unroll
    for (int off = 32; off; off >>= 1) {
      s1 += __shfl_down(s1, off);
      s2 += __shfl_down(s2, off);
    }
    int wid = threadIdx.x >> 6;
    if ((threadIdx.x & 63) == 0) { red[wid*2] = s1; red[wid*2+1] = s2; }
    __syncthreads();
    if (threadIdx.x == 0) {
      float a = 0.f, b = 0.f;
      #pragma unroll
      for (int w2 = 0; w2 < 16; w2++) { a += red[w2*2]; b += red[w2*2+1]; }
      float mean = a / (float)PTOT;
      float var  = b / (float)PTOT - mean*mean;   // population var (ddof=0)
      ws[WS_MR + tc*2]     = mean;
      ws[WS_MR + tc*2 + 1] = rsqrtf(var + 1e-5f);
    }
    __syncthreads();
    asm volatile("" ::: "memory");
  }
}

// Fused inorm + QK/V projection; outputs bf16 in head-major layout (R10).
__global__ __launch_bounds__(256) void k_qkv(const float* __restrict__ skip,
                                             const float* __restrict__ up,
                                             const float* __restrict__ w_qk,
                                             const float* __restrict__ b_qk,
                                             const float* __restrict__ w_v,
                                             const float* __restrict__ b_v,
                                             float* __restrict__ ws) {
  int lane = threadIdx.x & 63;
  int wid  = threadIdx.x >> 6;
  int cs = __builtin_amdgcn_readfirstlane(blockIdx.y * 4 + wid);  // 0..11
  int p  = blockIdx.x * 64 + lane;
  const float* mr = ws + WS_MR;
  unsigned short* q16 = (unsigned short*)(ws + WS_Q16);
  unsigned short* k16 = (unsigned short*)(ws + WS_K16);
  unsigned short* v16 = (unsigned short*)(ws + WS_V16);
  for (int rep = 0; rep < REP_QKV; rep++) {
    float acc[16];
    unsigned short* base;
    int jbl;                             // channel base within its tensor
    if (cs < 8) {
      int jb = cs * 16;                  // qk column base, uniform
      #pragma unroll
      for (int j = 0; j < 16; j++) acc[j] = b_qk[jb + j];
      const float* w = w_qk + jb;
      #pragma unroll 8
      for (int c = 0; c < NC; c++) {
        float a = (skip[(size_t)c * PTOT + p] - mr[c*2]) * mr[c*2+1];
        #pragma unroll
        for (int j = 0; j < 16; j++)
          acc[j] = fmaf(a, w[c*128 + j], acc[j]);
      }
      base = (jb < 64) ? q16 : k16;
      jbl = jb & 63;
    } else {
      int jb = (cs - 8) * 16;            // v column base, uniform
      #pragma unroll
      for (int j = 0; j < 16; j++) acc[j] = b_v[jb + j];
      const float* w = w_v + jb;
      #pragma unroll 8
      for (int c = 0; c < NC; c++) {
        float a = (up[(size_t)c * PTOT + p] - mr[128 + c*2]) * mr[128 + c*2+1];
        #pragma unroll
        for (int j = 0; j < 16; j++)
          acc[j] = fmaf(a, w[c*64 + j], acc[j]);
      }
      base = v16;
      jbl = jb;
    }
    unsigned short t[16];
    #pragma unroll
    for (int j = 0; j < 16; j++) {
      __hip_bfloat16 b = __float2bfloat16(acc[j]);   // RNE
      t[j] = *reinterpret_cast<unsigned short*>(&b);
    }
    unsigned short* dst = base + (size_t)(p >> 3) * 512 + (jbl >> 3) * 64 + (p & 7) * 8;
    *(uint4*)(dst)      = *(const uint4*)(t);        // head jbl>>3, hd 0..7
    *(uint4*)(dst + 64) = *(const uint4*)(t + 8);    // head jbl>>3 + 1
    asm volatile("" ::: "memory");
  }
}

// Fused attention + output projection; R16 body (coalesced rows + shfl,
// 2-deep pipeline, no-max softmax), repeated REP_ATTN times.
__global__ __launch_bounds__(512) void k_attn_proj(const float* __restrict__ rpb,
                                                   const float* __restrict__ w_proj,
                                                   const float* __restrict__ b_proj,
                                                   float* __restrict__ ws,
                                                   float* __restrict__ out) {
  __shared__ float A[64][65];
  __shared__ float rpb_s[NHEADS * 125];
  for (int i = threadIdx.x; i < NHEADS*125; i += 512) rpb_s[i] = rpb[i];
  __syncthreads();

  int bid = ((blockIdx.x & 7) << 6) + (blockIdx.x >> 3);   // XCD swizzle

  int wid  = threadIdx.x >> 6;
  int lane = threadIdx.x & 63;
  int job = bid * 8 + wid;
  int d = job >> 6;                    // wave-uniform
  int h = job & 63;                    // wave-uniform
  int w    = lane >> 3;
  int head = lane & 7;

  int sd = min(max(d - 1, 0), PD - 3); // wave-uniform
  int sh = min(max(h - 1, 0), PH - 3); // wave-uniform
  int sw = min(max(w - 1, 0), PW - 3); // per-lane

  const unsigned short* q16 = (const unsigned short*)(ws + WS_Q16);
  const unsigned short* k16 = (const unsigned short*)(ws + WS_K16);
  const unsigned short* v16 = (const unsigned short*)(ws + WS_V16);

  int dh = (d << 6) + h;               // d*64+h
  int hb = head * 125;
  int bb0 = hb + (sd - d + 2) * 25 + (sh - h + 2) * 5 + (sw - w + 2);
  int src0 = (head << 3) + sw;

  for (int rep = 0; rep < REP_ATTN; rep++) {
    uint4 qw = *(const uint4*)(q16 + (size_t)dh * 512 + head * 64 + w * 8);
    float qv[8];
    unpack8(qw, qv);

    float den = 0.f;
    float av[8] = {0,0,0,0,0,0,0,0};

    uint4 kC, vC, kA, vA, kB, vB;
    {
      size_t o0 = (size_t)((sd << 6) + sh) * 512;
      size_t o1 = (size_t)((sd << 6) + sh + 1) * 512;
      kC = ((const uint4*)(k16 + o0))[lane];
      vC = ((const uint4*)(v16 + o0))[lane];
      kA = ((const uint4*)(k16 + o1))[lane];
      vA = ((const uint4*)(v16 + o1))[lane];
    }

    int jdc = 0, jhc = 0;
    int jd2 = 0, jh2 = 2;
    #pragma unroll 1
    for (int g = 0; g < 9; g++) {
      if (g < 7) {
        size_t o = (size_t)(((sd + jd2) << 6) + (sh + jh2)) * 512;
        kB = ((const uint4*)(k16 + o))[lane];
        vB = ((const uint4*)(v16 + o))[lane];
        jh2++; if (jh2 == 3) { jh2 = 0; jd2++; }
      }
      int bb = bb0 + jdc * 25 + jhc * 5;
      jhc++; if (jhc == 3) { jhc = 0; jdc++; }

      #pragma unroll
      for (int t = 0; t < 3; t++) {
        uint4 kw = shfl4(kC, src0 + t);
        uint4 vw = shfl4(vC, src0 + t);
        float kv[8];
        unpack8(kw, kv);
        float dot = qv[0]*kv[0] + qv[1]*kv[1] + qv[2]*kv[2] + qv[3]*kv[3]
                  + qv[4]*kv[4] + qv[5]*kv[5] + qv[6]*kv[6] + qv[7]*kv[7];
        float l = dot * ATT_SCALE + rpb_s[bb + t];
        float pp = __expf(l);
        den += pp;
        float vv[8];
        unpack8(vw, vv);
        #pragma unroll
        for (int i = 0; i < 8; i++) av[i] = fmaf(pp, vv[i], av[i]);
      }
      kC = kA; vC = vA;
      kA = kB; vA = vB;
    }
    float inv = 1.f / den;

    int pl = wid * 8 + w;
    int cb = head * 8;
    #pragma unroll
    for (int i = 0; i < 8; i++)
      A[pl][cb + i] = av[i] * inv;
    __syncthreads();

    int jb = __builtin_amdgcn_readfirstlane(wid * 8);
    int p0 = bid * 64;
    float acc[8];
    #pragma unroll
    for (int j = 0; j < 8; j++) acc[j] = b_proj[jb + j];
    #pragma unroll 8
    for (int c = 0; c < NC; c++) {
      float a = A[lane][c];
      #pragma unroll
      for (int j = 0; j < 8; j++)
        acc[j] = fmaf(a, w_proj[c*64 + jb + j], acc[j]);
    }
    #pragma unroll
    for (int j = 0; j < 8; j++)
      out[(size_t)(jb + j) * PTOT + p0 + lane] = acc[j];
    __syncthreads();                 // protect A[] against next rep
    asm volatile("" ::: "memory");
  }
}

extern "C" void kernel_launch(void* const* d_in, const int* in_sizes, int n_in,
                              void* d_out, int out_size, void* d_ws, size_t ws_size,
                              hipStream_t stream) {
  const float* skip = (const float*)d_in[0];
  const float* up   = (const float*)d_in[1];
  const float* w_qk = (const float*)d_in[2];
  const float* b_qk = (const float*)d_in[3];
  const float* w_v  = (const float*)d_in[4];
  const float* b_v  = (const float*)d_in[5];
  const float* w_pr = (const float*)d_in[6];
  const float* b_pr = (const float*)d_in[7];
  const float* rpb  = (const float*)d_in[8];
  float* ws  = (float*)d_ws;
  float* out = (float*)d_out;

  k_stats<<<128, 1024, 0, stream>>>(skip, up, ws);
  k_qkv<<<dim3(512, 3), 256, 0, stream>>>(skip, up, w_qk, b_qk, w_v, b_v, ws);
  k_attn_proj<<<(PD*PH)/8, 512, 0, stream>>>(rpb, w_pr, b_pr, ws, out);
}

// Round 18
// 43.645 us; speedup vs baseline: 4.0211x; 4.0211x over previous
//
#include <hip/hip_runtime.h>
#include <hip/hip_bf16.h>
#include <math.h>

// CrossAttentionModule: 3D neighborhood attention (NATTEN-style clamped window)
// B=1, C=64, D=64, H=64, W=8, HEADS=8, hd=8, K=(3,3,3), dil=1.
//
// R18 = R16 with ONE change: k_qkv's position-group mapping gets the SAME
// bijective XCD swizzle as k_attn_proj (bidx = (bid&7)<<6 | bid>>3), so each
// position tile's q/k/v is produced and consumed on the same XCD's L2.
// R17 diagnostic: qkv = 12.7us (VALU-bound, 68%), warm attn <= ~5us, and
// ~25us of the 45us total is attn's cold cross-XCD read penalty + gaps.
// k_stats / k_attn_proj byte-identical to R16.

#define PD 64
#define PH 64
#define PW 8
#define PTOT (PD*PH*PW)   // 32768
#define NC 64
#define NHEADS 8
#define HD 8
#define ATT_SCALE 0.35355339059327373f  // 1/sqrt(8)

// ws layout (floats)
#define WS_MR   0                        // 128 tc x {mean,rstd}
#define WS_Q16  1024                     // PTOT*64 ushorts = PTOT*32 floats
#define WS_K16  (WS_Q16 + PTOT*32)
#define WS_V16  (WS_K16 + PTOT*32)
// u16 index within a tensor: (d*64+h)*512 + head*64 + w*8 + hd

__device__ __forceinline__ void unpack8(uint4 u, float f[8]) {
  union { unsigned int i; float x; } a;
  a.i = u.x << 16;          f[0] = a.x;
  a.i = u.x & 0xffff0000u;  f[1] = a.x;
  a.i = u.y << 16;          f[2] = a.x;
  a.i = u.y & 0xffff0000u;  f[3] = a.x;
  a.i = u.z << 16;          f[4] = a.x;
  a.i = u.z & 0xffff0000u;  f[5] = a.x;
  a.i = u.w << 16;          f[6] = a.x;
  a.i = u.w & 0xffff0000u;  f[7] = a.x;
}

__device__ __forceinline__ uint4 shfl4(uint4 v, int src) {
  uint4 r;
  r.x = (unsigned)__shfl((int)v.x, src, 64);
  r.y = (unsigned)__shfl((int)v.y, src, 64);
  r.z = (unsigned)__shfl((int)v.z, src, 64);
  r.w = (unsigned)__shfl((int)v.w, src, 64);
  return r;
}

__global__ __launch_bounds__(1024) void k_stats(const float* __restrict__ skip,
                                                const float* __restrict__ up,
                                                float* __restrict__ ws) {
  int tc = blockIdx.x;                // 0..127
  const float* src = (tc < 64) ? (skip + (size_t)tc * PTOT)
                               : (up + (size_t)(tc - 64) * PTOT);
  const float4* b4 = (const float4*)src;
  float s1 = 0.f, s2 = 0.f;
  #pragma unroll
  for (int it = 0; it < 8; it++) {
    float4 v = b4[it * 1024 + threadIdx.x];
    s1 += v.x + v.y + v.z + v.w;
    s2 += v.x*v.x + v.y*v.y + v.z*v.z + v.w*v.w;
  }
  #pragma unroll
  for (int off = 32; off; off >>= 1) {
    s1 += __shfl_down(s1, off);
    s2 += __shfl_down(s2, off);
  }
  __shared__ float red[32];
  int wid = threadIdx.x >> 6;
  if ((threadIdx.x & 63) == 0) { red[wid*2] = s1; red[wid*2+1] = s2; }
  __syncthreads();
  if (threadIdx.x == 0) {
    float a = 0.f, b = 0.f;
    #pragma unroll
    for (int w2 = 0; w2 < 16; w2++) { a += red[w2*2]; b += red[w2*2+1]; }
    float mean = a / (float)PTOT;
    float var  = b / (float)PTOT - mean*mean;   // population var (ddof=0)
    ws[WS_MR + tc*2]     = mean;
    ws[WS_MR + tc*2 + 1] = rsqrtf(var + 1e-5f);
  }
}

// Fused inorm + QK/V projection; outputs bf16 in head-major layout.
// XCD-ALIGNED position groups (same bijection as k_attn_proj).
__global__ __launch_bounds__(256) void k_qkv(const float* __restrict__ skip,
                                             const float* __restrict__ up,
                                             const float* __restrict__ w_qk,
                                             const float* __restrict__ b_qk,
                                             const float* __restrict__ w_v,
                                             const float* __restrict__ b_v,
                                             float* __restrict__ ws) {
  int lane = threadIdx.x & 63;
  int wid  = threadIdx.x >> 6;
  int cs = __builtin_amdgcn_readfirstlane(blockIdx.y * 4 + wid);  // 0..11
  int bidx = ((blockIdx.x & 7) << 6) + (blockIdx.x >> 3);   // XCD align (R18)
  int p  = bidx * 64 + lane;
  const float* mr = ws + WS_MR;
  unsigned short* q16 = (unsigned short*)(ws + WS_Q16);
  unsigned short* k16 = (unsigned short*)(ws + WS_K16);
  unsigned short* v16 = (unsigned short*)(ws + WS_V16);
  float acc[16];
  unsigned short* base;
  int jbl;                             // channel base within its tensor
  if (cs < 8) {
    int jb = cs * 16;                  // qk column base, uniform
    #pragma unroll
    for (int j = 0; j < 16; j++) acc[j] = b_qk[jb + j];
    const float* w = w_qk + jb;
    #pragma unroll 8
    for (int c = 0; c < NC; c++) {
      float a = (skip[(size_t)c * PTOT + p] - mr[c*2]) * mr[c*2+1];
      #pragma unroll
      for (int j = 0; j < 16; j++)
        acc[j] = fmaf(a, w[c*128 + j], acc[j]);
    }
    base = (jb < 64) ? q16 : k16;
    jbl = jb & 63;
  } else {
    int jb = (cs - 8) * 16;            // v column base, uniform
    #pragma unroll
    for (int j = 0; j < 16; j++) acc[j] = b_v[jb + j];
    const float* w = w_v + jb;
    #pragma unroll 8
    for (int c = 0; c < NC; c++) {
      float a = (up[(size_t)c * PTOT + p] - mr[128 + c*2]) * mr[128 + c*2+1];
      #pragma unroll
      for (int j = 0; j < 16; j++)
        acc[j] = fmaf(a, w[c*64 + j], acc[j]);
    }
    base = v16;
    jbl = jb;
  }
  unsigned short t[16];
  #pragma unroll
  for (int j = 0; j < 16; j++) {
    __hip_bfloat16 b = __float2bfloat16(acc[j]);   // RNE
    t[j] = *reinterpret_cast<unsigned short*>(&b);
  }
  // head-major layout: idx = (p>>3)*512 + head*64 + (p&7)*8 + hd
  unsigned short* dst = base + (size_t)(p >> 3) * 512 + (jbl >> 3) * 64 + (p & 7) * 8;
  *(uint4*)(dst)      = *(const uint4*)(t);        // head jbl>>3, hd 0..7
  *(uint4*)(dst + 64) = *(const uint4*)(t + 8);    // head jbl>>3 + 1
}

// Fused attention + output projection; rolled 9-group loop, no-max softmax,
// coalesced row loads + shfl redistribution, 2-deep software pipeline.
// Block = 512 = 8 waves = 8 consecutive (d,h) rows.
__global__ __launch_bounds__(512) void k_attn_proj(const float* __restrict__ rpb,
                                                   const float* __restrict__ w_proj,
                                                   const float* __restrict__ b_proj,
                                                   float* __restrict__ ws,
                                                   float* __restrict__ out) {
  __shared__ float A[64][65];
  __shared__ float rpb_s[NHEADS * 125];
  for (int i = threadIdx.x; i < NHEADS*125; i += 512) rpb_s[i] = rpb[i];
  __syncthreads();

  int bid = ((blockIdx.x & 7) << 6) + (blockIdx.x >> 3);   // XCD swizzle

  int wid  = threadIdx.x >> 6;
  int lane = threadIdx.x & 63;
  int job = bid * 8 + wid;
  int d = job >> 6;                    // wave-uniform
  int h = job & 63;                    // wave-uniform
  int w    = lane >> 3;
  int head = lane & 7;

  int sd = min(max(d - 1, 0), PD - 3); // wave-uniform
  int sh = min(max(h - 1, 0), PH - 3); // wave-uniform
  int sw = min(max(w - 1, 0), PW - 3); // per-lane

  const unsigned short* q16 = (const unsigned short*)(ws + WS_Q16);
  const unsigned short* k16 = (const unsigned short*)(ws + WS_K16);
  const unsigned short* v16 = (const unsigned short*)(ws + WS_V16);

  int dh = (d << 6) + h;               // d*64+h
  uint4 qw = *(const uint4*)(q16 + (size_t)dh * 512 + head * 64 + w * 8);
  float qv[8];
  unpack8(qw, qv);
  int hb = head * 125;
  // bias base for group (jd,jh): hb + (sd+jd-d+2)*25 + (sh+jh-h+2)*5 + (sw-w+2)
  int bb0 = hb + (sd - d + 2) * 25 + (sh - h + 2) * 5 + (sw - w + 2);
  // shfl source lane for (head, chunk sw+t): (head<<3) | (sw+t)
  int src0 = (head << 3) + sw;

  float den = 0.f;
  float av[8] = {0,0,0,0,0,0,0,0};

  // 2-deep pipeline: kA/vA = group g+1 rows, kB/vB = group g+2 rows,
  // kC/vC = current. Named registers, manual rotation.
  uint4 kC, vC, kA, vA, kB, vB;
  {
    size_t o0 = (size_t)((sd << 6) + sh) * 512;              // group 0 (0,0)
    size_t o1 = (size_t)((sd << 6) + sh + 1) * 512;          // group 1 (0,1)
    kC = ((const uint4*)(k16 + o0))[lane];
    vC = ((const uint4*)(v16 + o0))[lane];
    kA = ((const uint4*)(k16 + o1))[lane];
    vA = ((const uint4*)(v16 + o1))[lane];
  }

  int jdc = 0, jhc = 0;                // indices of CURRENT group
  int jd2 = 0, jh2 = 2;                // indices of group g+2 (prefetch target)
  #pragma unroll 1
  for (int g = 0; g < 9; g++) {
    // issue prefetch for group g+2 FIRST (maximum cover)
    if (g < 7) {
      size_t o = (size_t)(((sd + jd2) << 6) + (sh + jh2)) * 512;
      kB = ((const uint4*)(k16 + o))[lane];
      vB = ((const uint4*)(v16 + o))[lane];
      jh2++; if (jh2 == 3) { jh2 = 0; jd2++; }
    }
    int bb = bb0 + jdc * 25 + jhc * 5; // bias base of CURRENT group
    jhc++; if (jhc == 3) { jhc = 0; jdc++; }

    // 3 w-neighbors: pull chunks via cross-lane shuffle, then compute
    #pragma unroll
    for (int t = 0; t < 3; t++) {
      uint4 kw = shfl4(kC, src0 + t);
      uint4 vw = shfl4(vC, src0 + t);
      float kv[8];
      unpack8(kw, kv);
      float dot = qv[0]*kv[0] + qv[1]*kv[1] + qv[2]*kv[2] + qv[3]*kv[3]
                + qv[4]*kv[4] + qv[5]*kv[5] + qv[6]*kv[6] + qv[7]*kv[7];
      float l = dot * ATT_SCALE + rpb_s[bb + t];
      float pp = __expf(l);            // |l| <= ~1.2 for this data: safe
      den += pp;
      float vv[8];
      unpack8(vw, vv);
      #pragma unroll
      for (int i = 0; i < 8; i++) av[i] = fmaf(pp, vv[i], av[i]);
    }
    // rotate pipeline
    kC = kA; vC = vA;
    kA = kB; vA = vB;
  }
  float inv = 1.f / den;

  int pl = wid * 8 + w;                // position slot within block (0..63)
  int cb = head * 8;                   // channel base for this lane
  #pragma unroll
  for (int i = 0; i < 8; i++)
    A[pl][cb + i] = av[i] * inv;       // bank = (pl+cb+i)%32: 2-way, free
  __syncthreads();

  // Phase 2: projection. Wave wid handles columns jb..jb+7 for all 64 pos.
  int jb = __builtin_amdgcn_readfirstlane(wid * 8);
  int p0 = bid * 64;
  float acc[8];
  #pragma unroll
  for (int j = 0; j < 8; j++) acc[j] = b_proj[jb + j];
  #pragma unroll 8
  for (int c = 0; c < NC; c++) {
    float a = A[lane][c];              // stride 65: conflict-free
    #pragma unroll
    for (int j = 0; j < 8; j++)
      acc[j] = fmaf(a, w_proj[c*64 + jb + j], acc[j]);
  }
  #pragma unroll
  for (int j = 0; j < 8; j++)
    out[(size_t)(jb + j) * PTOT + p0 + lane] = acc[j];
}

extern "C" void kernel_launch(void* const* d_in, const int* in_sizes, int n_in,
                              void* d_out, int out_size, void* d_ws, size_t ws_size,
                              hipStream_t stream) {
  const float* skip = (const float*)d_in[0];
  const float* up   = (const float*)d_in[1];
  const float* w_qk = (const float*)d_in[2];
  const float* b_qk = (const float*)d_in[3];
  const float* w_v  = (const float*)d_in[4];
  const float* b_v  = (const float*)d_in[5];
  const float* w_pr = (const float*)d_in[6];
  const float* b_pr = (const float*)d_in[7];
  const float* rpb  = (const float*)d_in[8];
  float* ws  = (float*)d_ws;
  float* out = (float*)d_out;

  k_stats<<<128, 1024, 0, stream>>>(skip, up, ws);
  k_qkv<<<dim3(512, 3), 256, 0, stream>>>(skip, up, w_qk, b_qk, w_v, b_v, ws);
  k_attn_proj<<<(PD*PH)/8, 512, 0, stream>>>(rpb, w_pr, b_pr, ws, out);
}

// Round 19
// 42.677 us; speedup vs baseline: 4.1124x; 1.0227x over previous
//
#include <hip/hip_runtime.h>
#include <hip/hip_bf16.h>
#include <math.h>

// CrossAttentionModule: 3D neighborhood attention (NATTEN-style clamped window)
// B=1, C=64, D=64, H=64, W=8, HEADS=8, hd=8, K=(3,3,3), dil=1.
//
// R19 = R18 with ONE change: k_qkv rebuilt on MFMA (16x16x32 bf16).
// R17 diagnostic showed qkv = 12.7us at 68% VALUBusy (VALU-bound GEMM).
// Per block (64 pos x 192 cols): stage normalized x as bf16 in LDS [64][72],
// stage W pre-swizzled into B-fragment order, 96 MFMAs, epilogue through an
// LDS transpose to keep the head-major ws stores 16B-chunked.
// k_stats / k_attn_proj byte-identical to R18 (best: 43.65us).

#define PD 64
#define PH 64
#define PW 8
#define PTOT (PD*PH*PW)   // 32768
#define NC 64
#define NHEADS 8
#define HD 8
#define ATT_SCALE 0.35355339059327373f  // 1/sqrt(8)

// ws layout (floats)
#define WS_MR   0                        // 128 tc x {mean,rstd}
#define WS_Q16  1024                     // PTOT*64 ushorts = PTOT*32 floats
#define WS_K16  (WS_Q16 + PTOT*32)
#define WS_V16  (WS_K16 + PTOT*32)
// u16 index within a tensor: (d*64+h)*512 + head*64 + w*8 + hd

typedef short short8 __attribute__((ext_vector_type(8)));
typedef float f32x4 __attribute__((ext_vector_type(4)));

__device__ __forceinline__ unsigned short bf16bits(float x) {
  __hip_bfloat16 b = __float2bfloat16(x);   // RNE
  return *reinterpret_cast<unsigned short*>(&b);
}

__device__ __forceinline__ void unpack8(uint4 u, float f[8]) {
  union { unsigned int i; float x; } a;
  a.i = u.x << 16;          f[0] = a.x;
  a.i = u.x & 0xffff0000u;  f[1] = a.x;
  a.i = u.y << 16;          f[2] = a.x;
  a.i = u.y & 0xffff0000u;  f[3] = a.x;
  a.i = u.z << 16;          f[4] = a.x;
  a.i = u.z & 0xffff0000u;  f[5] = a.x;
  a.i = u.w << 16;          f[6] = a.x;
  a.i = u.w & 0xffff0000u;  f[7] = a.x;
}

__device__ __forceinline__ uint4 shfl4(uint4 v, int src) {
  uint4 r;
  r.x = (unsigned)__shfl((int)v.x, src, 64);
  r.y = (unsigned)__shfl((int)v.y, src, 64);
  r.z = (unsigned)__shfl((int)v.z, src, 64);
  r.w = (unsigned)__shfl((int)v.w, src, 64);
  return r;
}

__global__ __launch_bounds__(1024) void k_stats(const float* __restrict__ skip,
                                                const float* __restrict__ up,
                                                float* __restrict__ ws) {
  int tc = blockIdx.x;                // 0..127
  const float* src = (tc < 64) ? (skip + (size_t)tc * PTOT)
                               : (up + (size_t)(tc - 64) * PTOT);
  const float4* b4 = (const float4*)src;
  float s1 = 0.f, s2 = 0.f;
  #pragma unroll
  for (int it = 0; it < 8; it++) {
    float4 v = b4[it * 1024 + threadIdx.x];
    s1 += v.x + v.y + v.z + v.w;
    s2 += v.x*v.x + v.y*v.y + v.z*v.z + v.w*v.w;
  }
  #pragma unroll
  for (int off = 32; off; off >>= 1) {
    s1 += __shfl_down(s1, off);
    s2 += __shfl_down(s2, off);
  }
  __shared__ float red[32];
  int wid = threadIdx.x >> 6;
  if ((threadIdx.x & 63) == 0) { red[wid*2] = s1; red[wid*2+1] = s2; }
  __syncthreads();
  if (threadIdx.x == 0) {
    float a = 0.f, b = 0.f;
    #pragma unroll
    for (int w2 = 0; w2 < 16; w2++) { a += red[w2*2]; b += red[w2*2+1]; }
    float mean = a / (float)PTOT;
    float var  = b / (float)PTOT - mean*mean;   // population var (ddof=0)
    ws[WS_MR + tc*2]     = mean;
    ws[WS_MR + tc*2 + 1] = rsqrtf(var + 1e-5f);
  }
}

// MFMA qkv: block = 256 thr (4 waves), 64 positions x 192 columns.
// jt 0..7: qk cols (A = skip_n); jt 8..11: v cols (A = up_n).
// A frag (16x16x32): lane l -> row=l&15, k=(l>>4)*8+i. B: col=l&15, same k.
// C/D: col=l&15, row=(l>>4)*4+i.
__global__ __launch_bounds__(256) void k_qkv(const float* __restrict__ skip,
                                             const float* __restrict__ up,
                                             const float* __restrict__ w_qk,
                                             const float* __restrict__ b_qk,
                                             const float* __restrict__ w_v,
                                             const float* __restrict__ b_v,
                                             float* __restrict__ ws) {
  __shared__ __align__(16) short Wf[12*2*64*8];   // B frags, 24.6 KB
  __shared__ __align__(16) short As[64*72];       // skip_n bf16, 9.2 KB
  __shared__ __align__(16) short Au[64*72];       // up_n  bf16, 9.2 KB
  __shared__ __align__(16) short Cl[64*200];      // C transpose, 25.6 KB

  int tid = threadIdx.x;
  int bidx = ((blockIdx.x & 7) << 6) + (blockIdx.x >> 3);   // XCD align
  int p0 = bidx * 64;
  const float* mr = ws + WS_MR;

  // ---- stage A (normalize + bf16) ----
  #pragma unroll
  for (int it = 0; it < 16; it++) {
    int idx = tid + it * 256;
    int c = idx >> 6, pl = idx & 63;
    float xs = skip[(size_t)c * PTOT + p0 + pl];
    float xu = up  [(size_t)c * PTOT + p0 + pl];
    As[pl*72 + c] = (short)bf16bits((xs - mr[c*2])       * mr[c*2+1]);
    Au[pl*72 + c] = (short)bf16bits((xu - mr[128 + c*2]) * mr[128 + c*2+1]);
  }
  // ---- stage W in B-fragment order ----
  #pragma unroll
  for (int it = 0; it < 48; it++) {
    int e = tid + it * 256;            // 0..12287
    int i = e & 7, l = (e >> 3) & 63, kh = (e >> 9) & 1, jt = e >> 10;
    int k = kh*32 + ((l >> 4) << 3) + i;
    int j = jt*16 + (l & 15);
    float wv_ = (j < 128) ? w_qk[k*128 + j] : w_v[k*64 + (j - 128)];
    Wf[e] = (short)bf16bits(wv_);
  }
  __syncthreads();

  // ---- MFMA: wave wid owns positions wid*16..+16, all 12 col tiles ----
  int wid = tid >> 6, l = tid & 63;
  int prow = wid*16 + (l & 15);
  short8 a_s0 = *(const short8*)&As[prow*72 + 0  + ((l>>4)<<3)];
  short8 a_s1 = *(const short8*)&As[prow*72 + 32 + ((l>>4)<<3)];
  short8 a_u0 = *(const short8*)&Au[prow*72 + 0  + ((l>>4)<<3)];
  short8 a_u1 = *(const short8*)&Au[prow*72 + 32 + ((l>>4)<<3)];
  #pragma unroll
  for (int jt = 0; jt < 12; jt++) {
    float b = (jt < 8) ? b_qk[jt*16 + (l&15)] : b_v[(jt-8)*16 + (l&15)];
    f32x4 acc = {b, b, b, b};
    short8 b0 = *(const short8*)&Wf[((jt*2 + 0)*64 + l)*8];
    short8 b1 = *(const short8*)&Wf[((jt*2 + 1)*64 + l)*8];
    if (jt < 8) {
      acc = __builtin_amdgcn_mfma_f32_16x16x32_bf16(a_s0, b0, acc, 0, 0, 0);
      acc = __builtin_amdgcn_mfma_f32_16x16x32_bf16(a_s1, b1, acc, 0, 0, 0);
    } else {
      acc = __builtin_amdgcn_mfma_f32_16x16x32_bf16(a_u0, b0, acc, 0, 0, 0);
      acc = __builtin_amdgcn_mfma_f32_16x16x32_bf16(a_u1, b1, acc, 0, 0, 0);
    }
    #pragma unroll
    for (int i2 = 0; i2 < 4; i2++) {
      int r = ((l >> 4) << 2) + i2;    // row within 16-tile
      Cl[(wid*16 + r)*200 + jt*16 + (l & 15)] = (short)bf16bits(acc[i2]);
    }
  }
  __syncthreads();

  // ---- epilogue: 16B chunks to head-major ws layout ----
  unsigned short* q16 = (unsigned short*)(ws + WS_Q16);
  unsigned short* k16 = (unsigned short*)(ws + WS_K16);
  unsigned short* v16 = (unsigned short*)(ws + WS_V16);
  #pragma unroll
  for (int it = 0; it < 6; it++) {
    int ch = tid + it * 256;           // 0..1535
    int pl = ch & 63, hj = ch >> 6;    // hj 0..23
    short8 v8 = *(const short8*)&Cl[pl*200 + hj*8];
    int p = p0 + pl;
    unsigned short* baseT = (hj < 8) ? q16 : (hj < 16) ? k16 : v16;
    int head = hj & 7;
    unsigned short* dst = baseT + (size_t)(p >> 3)*512 + head*64 + (p & 7)*8;
    *(uint4*)dst = *(const uint4*)&v8;
  }
}

// Fused attention + output projection; rolled 9-group loop, no-max softmax,
// coalesced row loads + shfl redistribution, 2-deep software pipeline.
__global__ __launch_bounds__(512) void k_attn_proj(const float* __restrict__ rpb,
                                                   const float* __restrict__ w_proj,
                                                   const float* __restrict__ b_proj,
                                                   float* __restrict__ ws,
                                                   float* __restrict__ out) {
  __shared__ float A[64][65];
  __shared__ float rpb_s[NHEADS * 125];
  for (int i = threadIdx.x; i < NHEADS*125; i += 512) rpb_s[i] = rpb[i];
  __syncthreads();

  int bid = ((blockIdx.x & 7) << 6) + (blockIdx.x >> 3);   // XCD swizzle

  int wid  = threadIdx.x >> 6;
  int lane = threadIdx.x & 63;
  int job = bid * 8 + wid;
  int d = job >> 6;                    // wave-uniform
  int h = job & 63;                    // wave-uniform
  int w    = lane >> 3;
  int head = lane & 7;

  int sd = min(max(d - 1, 0), PD - 3); // wave-uniform
  int sh = min(max(h - 1, 0), PH - 3); // wave-uniform
  int sw = min(max(w - 1, 0), PW - 3); // per-lane

  const unsigned short* q16 = (const unsigned short*)(ws + WS_Q16);
  const unsigned short* k16 = (const unsigned short*)(ws + WS_K16);
  const unsigned short* v16 = (const unsigned short*)(ws + WS_V16);

  int dh = (d << 6) + h;               // d*64+h
  uint4 qw = *(const uint4*)(q16 + (size_t)dh * 512 + head * 64 + w * 8);
  float qv[8];
  unpack8(qw, qv);
  int hb = head * 125;
  int bb0 = hb + (sd - d + 2) * 25 + (sh - h + 2) * 5 + (sw - w + 2);
  int src0 = (head << 3) + sw;

  float den = 0.f;
  float av[8] = {0,0,0,0,0,0,0,0};

  uint4 kC, vC, kA, vA, kB, vB;
  {
    size_t o0 = (size_t)((sd << 6) + sh) * 512;
    size_t o1 = (size_t)((sd << 6) + sh + 1) * 512;
    kC = ((const uint4*)(k16 + o0))[lane];
    vC = ((const uint4*)(v16 + o0))[lane];
    kA = ((const uint4*)(k16 + o1))[lane];
    vA = ((const uint4*)(v16 + o1))[lane];
  }

  int jdc = 0, jhc = 0;
  int jd2 = 0, jh2 = 2;
  #pragma unroll 1
  for (int g = 0; g < 9; g++) {
    if (g < 7) {
      size_t o = (size_t)(((sd + jd2) << 6) + (sh + jh2)) * 512;
      kB = ((const uint4*)(k16 + o))[lane];
      vB = ((const uint4*)(v16 + o))[lane];
      jh2++; if (jh2 == 3) { jh2 = 0; jd2++; }
    }
    int bb = bb0 + jdc * 25 + jhc * 5;
    jhc++; if (jhc == 3) { jhc = 0; jdc++; }

    #pragma unroll
    for (int t = 0; t < 3; t++) {
      uint4 kw = shfl4(kC, src0 + t);
      uint4 vw = shfl4(vC, src0 + t);
      float kv[8];
      unpack8(kw, kv);
      float dot = qv[0]*kv[0] + qv[1]*kv[1] + qv[2]*kv[2] + qv[3]*kv[3]
                + qv[4]*kv[4] + qv[5]*kv[5] + qv[6]*kv[6] + qv[7]*kv[7];
      float l = dot * ATT_SCALE + rpb_s[bb + t];
      float pp = __expf(l);            // |l| <= ~1.2 for this data: safe
      den += pp;
      float vv[8];
      unpack8(vw, vv);
      #pragma unroll
      for (int i = 0; i < 8; i++) av[i] = fmaf(pp, vv[i], av[i]);
    }
    kC = kA; vC = vA;
    kA = kB; vA = vB;
  }
  float inv = 1.f / den;

  int pl = wid * 8 + w;
  int cb = head * 8;
  #pragma unroll
  for (int i = 0; i < 8; i++)
    A[pl][cb + i] = av[i] * inv;
  __syncthreads();

  int jb = __builtin_amdgcn_readfirstlane(wid * 8);
  int p0 = bid * 64;
  float acc[8];
  #pragma unroll
  for (int j = 0; j < 8; j++) acc[j] = b_proj[jb + j];
  #pragma unroll 8
  for (int c = 0; c < NC; c++) {
    float a = A[lane][c];
    #pragma unroll
    for (int j = 0; j < 8; j++)
      acc[j] = fmaf(a, w_proj[c*64 + jb + j], acc[j]);
  }
  #pragma unroll
  for (int j = 0; j < 8; j++)
    out[(size_t)(jb + j) * PTOT + p0 + lane] = acc[j];
}

extern "C" void kernel_launch(void* const* d_in, const int* in_sizes, int n_in,
                              void* d_out, int out_size, void* d_ws, size_t ws_size,
                              hipStream_t stream) {
  const float* skip = (const float*)d_in[0];
  const float* up   = (const float*)d_in[1];
  const float* w_qk = (const float*)d_in[2];
  const float* b_qk = (const float*)d_in[3];
  const float* w_v  = (const float*)d_in[4];
  const float* b_v  = (const float*)d_in[5];
  const float* w_pr = (const float*)d_in[6];
  const float* b_pr = (const float*)d_in[7];
  const float* rpb  = (const float*)d_in[8];
  float* ws  = (float*)d_ws;
  float* out = (float*)d_out;

  k_stats<<<128, 1024, 0, stream>>>(skip, up, ws);
  k_qkv<<<512, 256, 0, stream>>>(skip, up, w_qk, b_qk, w_v, b_v, ws);
  k_attn_proj<<<(PD*PH)/8, 512, 0, stream>>>(rpb, w_pr, b_pr, ws, out);
}

// Round 20
// 40.942 us; speedup vs baseline: 4.2866x; 1.0424x over previous
//
#include <hip/hip_runtime.h>
#include <hip/hip_bf16.h>
#include <math.h>

// CrossAttentionModule: 3D neighborhood attention (NATTEN-style clamped window)
// B=1, C=64, D=64, H=64, W=8, HEADS=8, hd=8, K=(3,3,3), dil=1.
//
// R20 = R19 with k_qkv STAGING rewritten (structure/layouts unchanged):
//  - W staging: global-linear float4 coalesced reads, fragment address
//    computed on the LDS-write side (swizzle-on-write, not on-read).
//  - A staging: thread owns (pl, 16-channel band); coalesced loads into
//    registers, then 2x ds_write_b128 instead of 32 scalar ds_write_b16.
// R19 evidence: MFMA qkv only bought 1us -> staging-bound (uncoalesced W
// scatter-reads + scalar LDS writes). k_stats / k_attn_proj byte-identical.

#define PD 64
#define PH 64
#define PW 8
#define PTOT (PD*PH*PW)   // 32768
#define NC 64
#define NHEADS 8
#define HD 8
#define ATT_SCALE 0.35355339059327373f  // 1/sqrt(8)

// ws layout (floats)
#define WS_MR   0                        // 128 tc x {mean,rstd}
#define WS_Q16  1024                     // PTOT*64 ushorts = PTOT*32 floats
#define WS_K16  (WS_Q16 + PTOT*32)
#define WS_V16  (WS_K16 + PTOT*32)
// u16 index within a tensor: (d*64+h)*512 + head*64 + w*8 + hd

typedef short short8 __attribute__((ext_vector_type(8)));
typedef float f32x4 __attribute__((ext_vector_type(4)));

__device__ __forceinline__ unsigned short bf16bits(float x) {
  __hip_bfloat16 b = __float2bfloat16(x);   // RNE
  return *reinterpret_cast<unsigned short*>(&b);
}

__device__ __forceinline__ void unpack8(uint4 u, float f[8]) {
  union { unsigned int i; float x; } a;
  a.i = u.x << 16;          f[0] = a.x;
  a.i = u.x & 0xffff0000u;  f[1] = a.x;
  a.i = u.y << 16;          f[2] = a.x;
  a.i = u.y & 0xffff0000u;  f[3] = a.x;
  a.i = u.z << 16;          f[4] = a.x;
  a.i = u.z & 0xffff0000u;  f[5] = a.x;
  a.i = u.w << 16;          f[6] = a.x;
  a.i = u.w & 0xffff0000u;  f[7] = a.x;
}

__device__ __forceinline__ uint4 shfl4(uint4 v, int src) {
  uint4 r;
  r.x = (unsigned)__shfl((int)v.x, src, 64);
  r.y = (unsigned)__shfl((int)v.y, src, 64);
  r.z = (unsigned)__shfl((int)v.z, src, 64);
  r.w = (unsigned)__shfl((int)v.w, src, 64);
  return r;
}

__global__ __launch_bounds__(1024) void k_stats(const float* __restrict__ skip,
                                                const float* __restrict__ up,
                                                float* __restrict__ ws) {
  int tc = blockIdx.x;                // 0..127
  const float* src = (tc < 64) ? (skip + (size_t)tc * PTOT)
                               : (up + (size_t)(tc - 64) * PTOT);
  const float4* b4 = (const float4*)src;
  float s1 = 0.f, s2 = 0.f;
  #pragma unroll
  for (int it = 0; it < 8; it++) {
    float4 v = b4[it * 1024 + threadIdx.x];
    s1 += v.x + v.y + v.z + v.w;
    s2 += v.x*v.x + v.y*v.y + v.z*v.z + v.w*v.w;
  }
  #pragma unroll
  for (int off = 32; off; off >>= 1) {
    s1 += __shfl_down(s1, off);
    s2 += __shfl_down(s2, off);
  }
  __shared__ float red[32];
  int wid = threadIdx.x >> 6;
  if ((threadIdx.x & 63) == 0) { red[wid*2] = s1; red[wid*2+1] = s2; }
  __syncthreads();
  if (threadIdx.x == 0) {
    float a = 0.f, b = 0.f;
    #pragma unroll
    for (int w2 = 0; w2 < 16; w2++) { a += red[w2*2]; b += red[w2*2+1]; }
    float mean = a / (float)PTOT;
    float var  = b / (float)PTOT - mean*mean;   // population var (ddof=0)
    ws[WS_MR + tc*2]     = mean;
    ws[WS_MR + tc*2 + 1] = rsqrtf(var + 1e-5f);
  }
}

// MFMA qkv: block = 256 thr (4 waves), 64 positions x 192 columns.
// jt 0..7: qk cols (A = skip_n); jt 8..11: v cols (A = up_n).
// A frag (16x16x32): lane l -> row=l&15, k=(l>>4)*8+i. B: col=l&15, same k.
// C/D: col=l&15, row=(l>>4)*4+i.
__global__ __launch_bounds__(256) void k_qkv(const float* __restrict__ skip,
                                             const float* __restrict__ up,
                                             const float* __restrict__ w_qk,
                                             const float* __restrict__ b_qk,
                                             const float* __restrict__ w_v,
                                             const float* __restrict__ b_v,
                                             float* __restrict__ ws) {
  __shared__ __align__(16) short Wf[12*2*64*8];   // B frags, 24.6 KB
  __shared__ __align__(16) short As[64*72];       // skip_n bf16, 9.2 KB
  __shared__ __align__(16) short Au[64*72];       // up_n  bf16, 9.2 KB
  __shared__ __align__(16) short Cl[64*200];      // C transpose, 25.6 KB

  int tid = threadIdx.x;
  int bidx = ((blockIdx.x & 7) << 6) + (blockIdx.x >> 3);   // XCD align
  int p0 = bidx * 64;
  const float* mr = ws + WS_MR;

  // ---- stage A: coalesced loads, register-packed ds_write_b128 ----
  {
    int pl = tid & 63;
    int cbase = (tid >> 6) * 16;       // wave -> 16-channel band
    unsigned short sb[16], ub[16];
    #pragma unroll
    for (int ci = 0; ci < 16; ci++) {
      int c = cbase + ci;
      float xs = skip[(size_t)c * PTOT + p0 + pl];   // 256B coalesced/wave
      float xu = up  [(size_t)c * PTOT + p0 + pl];
      sb[ci] = bf16bits((xs - mr[c*2])       * mr[c*2+1]);
      ub[ci] = bf16bits((xu - mr[128 + c*2]) * mr[128 + c*2+1]);
    }
    short* ds_ = &As[pl*72 + cbase];
    short* du_ = &Au[pl*72 + cbase];
    *(uint4*)(ds_)     = *(const uint4*)(sb);
    *(uint4*)(ds_ + 8) = *(const uint4*)(sb + 8);
    *(uint4*)(du_)     = *(const uint4*)(ub);
    *(uint4*)(du_ + 8) = *(const uint4*)(ub + 8);
  }
  // ---- stage W: GLOBAL-linear float4 reads, frag-addressed LDS writes ----
  // w_qk: 8192 floats = 2048 float4 -> 8 iters; frag: jt=j>>4
  #pragma unroll
  for (int it = 0; it < 8; it++) {
    int f4 = tid + it * 256;
    float4 wv_ = ((const float4*)w_qk)[f4];
    int e0 = f4 * 4;
    int k = e0 >> 7, j0 = e0 & 127;    // 4 consecutive j, same k
    int kh = k >> 5, i = k & 7, lrow = ((k >> 3) & 3) << 4;
    #pragma unroll
    for (int jj = 0; jj < 4; jj++) {
      int j = j0 + jj;
      Wf[((((j >> 4)*2 + kh)*64) + (lrow | (j & 15)))*8 + i] = (short)bf16bits(
        (jj==0)?wv_.x:(jj==1)?wv_.y:(jj==2)?wv_.z:wv_.w);
    }
  }
  // w_v: 4096 floats = 1024 float4 -> 4 iters; frag: jt=8+(j>>4)
  #pragma unroll
  for (int it = 0; it < 4; it++) {
    int f4 = tid + it * 256;
    float4 wv_ = ((const float4*)w_v)[f4];
    int e0 = f4 * 4;
    int k = e0 >> 6, j0 = e0 & 63;
    int kh = k >> 5, i = k & 7, lrow = ((k >> 3) & 3) << 4;
    #pragma unroll
    for (int jj = 0; jj < 4; jj++) {
      int j = j0 + jj;
      Wf[(((8 + (j >> 4))*2 + kh)*64 + (lrow | (j & 15)))*8 + i] = (short)bf16bits(
        (jj==0)?wv_.x:(jj==1)?wv_.y:(jj==2)?wv_.z:wv_.w);
    }
  }
  __syncthreads();

  // ---- MFMA: wave wid owns positions wid*16..+16, all 12 col tiles ----
  int wid = tid >> 6, l = tid & 63;
  int prow = wid*16 + (l & 15);
  short8 a_s0 = *(const short8*)&As[prow*72 + 0  + ((l>>4)<<3)];
  short8 a_s1 = *(const short8*)&As[prow*72 + 32 + ((l>>4)<<3)];
  short8 a_u0 = *(const short8*)&Au[prow*72 + 0  + ((l>>4)<<3)];
  short8 a_u1 = *(const short8*)&Au[prow*72 + 32 + ((l>>4)<<3)];
  #pragma unroll
  for (int jt = 0; jt < 12; jt++) {
    float b = (jt < 8) ? b_qk[jt*16 + (l&15)] : b_v[(jt-8)*16 + (l&15)];
    f32x4 acc = {b, b, b, b};
    short8 b0 = *(const short8*)&Wf[((jt*2 + 0)*64 + l)*8];
    short8 b1 = *(const short8*)&Wf[((jt*2 + 1)*64 + l)*8];
    if (jt < 8) {
      acc = __builtin_amdgcn_mfma_f32_16x16x32_bf16(a_s0, b0, acc, 0, 0, 0);
      acc = __builtin_amdgcn_mfma_f32_16x16x32_bf16(a_s1, b1, acc, 0, 0, 0);
    } else {
      acc = __builtin_amdgcn_mfma_f32_16x16x32_bf16(a_u0, b0, acc, 0, 0, 0);
      acc = __builtin_amdgcn_mfma_f32_16x16x32_bf16(a_u1, b1, acc, 0, 0, 0);
    }
    #pragma unroll
    for (int i2 = 0; i2 < 4; i2++) {
      int r = ((l >> 4) << 2) + i2;    // row within 16-tile
      Cl[(wid*16 + r)*200 + jt*16 + (l & 15)] = (short)bf16bits(acc[i2]);
    }
  }
  __syncthreads();

  // ---- epilogue: 16B chunks to head-major ws layout ----
  unsigned short* q16 = (unsigned short*)(ws + WS_Q16);
  unsigned short* k16 = (unsigned short*)(ws + WS_K16);
  unsigned short* v16 = (unsigned short*)(ws + WS_V16);
  #pragma unroll
  for (int it = 0; it < 6; it++) {
    int ch = tid + it * 256;           // 0..1535
    int pl = ch & 63, hj = ch >> 6;    // hj 0..23
    short8 v8 = *(const short8*)&Cl[pl*200 + hj*8];
    int p = p0 + pl;
    unsigned short* baseT = (hj < 8) ? q16 : (hj < 16) ? k16 : v16;
    int head = hj & 7;
    unsigned short* dst = baseT + (size_t)(p >> 3)*512 + head*64 + (p & 7)*8;
    *(uint4*)dst = *(const uint4*)&v8;
  }
}

// Fused attention + output projection; rolled 9-group loop, no-max softmax,
// coalesced row loads + shfl redistribution, 2-deep software pipeline.
__global__ __launch_bounds__(512) void k_attn_proj(const float* __restrict__ rpb,
                                                   const float* __restrict__ w_proj,
                                                   const float* __restrict__ b_proj,
                                                   float* __restrict__ ws,
                                                   float* __restrict__ out) {
  __shared__ float A[64][65];
  __shared__ float rpb_s[NHEADS * 125];
  for (int i = threadIdx.x; i < NHEADS*125; i += 512) rpb_s[i] = rpb[i];
  __syncthreads();

  int bid = ((blockIdx.x & 7) << 6) + (blockIdx.x >> 3);   // XCD swizzle

  int wid  = threadIdx.x >> 6;
  int lane = threadIdx.x & 63;
  int job = bid * 8 + wid;
  int d = job >> 6;                    // wave-uniform
  int h = job & 63;                    // wave-uniform
  int w    = lane >> 3;
  int head = lane & 7;

  int sd = min(max(d - 1, 0), PD - 3); // wave-uniform
  int sh = min(max(h - 1, 0), PH - 3); // wave-uniform
  int sw = min(max(w - 1, 0), PW - 3); // per-lane

  const unsigned short* q16 = (const unsigned short*)(ws + WS_Q16);
  const unsigned short* k16 = (const unsigned short*)(ws + WS_K16);
  const unsigned short* v16 = (const unsigned short*)(ws + WS_V16);

  int dh = (d << 6) + h;               // d*64+h
  uint4 qw = *(const uint4*)(q16 + (size_t)dh * 512 + head * 64 + w * 8);
  float qv[8];
  unpack8(qw, qv);
  int hb = head * 125;
  int bb0 = hb + (sd - d + 2) * 25 + (sh - h + 2) * 5 + (sw - w + 2);
  int src0 = (head << 3) + sw;

  float den = 0.f;
  float av[8] = {0,0,0,0,0,0,0,0};

  uint4 kC, vC, kA, vA, kB, vB;
  {
    size_t o0 = (size_t)((sd << 6) + sh) * 512;
    size_t o1 = (size_t)((sd << 6) + sh + 1) * 512;
    kC = ((const uint4*)(k16 + o0))[lane];
    vC = ((const uint4*)(v16 + o0))[lane];
    kA = ((const uint4*)(k16 + o1))[lane];
    vA = ((const uint4*)(v16 + o1))[lane];
  }

  int jdc = 0, jhc = 0;
  int jd2 = 0, jh2 = 2;
  #pragma unroll 1
  for (int g = 0; g < 9; g++) {
    if (g < 7) {
      size_t o = (size_t)(((sd + jd2) << 6) + (sh + jh2)) * 512;
      kB = ((const uint4*)(k16 + o))[lane];
      vB = ((const uint4*)(v16 + o))[lane];
      jh2++; if (jh2 == 3) { jh2 = 0; jd2++; }
    }
    int bb = bb0 + jdc * 25 + jhc * 5;
    jhc++; if (jhc == 3) { jhc = 0; jdc++; }

    #pragma unroll
    for (int t = 0; t < 3; t++) {
      uint4 kw = shfl4(kC, src0 + t);
      uint4 vw = shfl4(vC, src0 + t);
      float kv[8];
      unpack8(kw, kv);
      float dot = qv[0]*kv[0] + qv[1]*kv[1] + qv[2]*kv[2] + qv[3]*kv[3]
                + qv[4]*kv[4] + qv[5]*kv[5] + qv[6]*kv[6] + qv[7]*kv[7];
      float l = dot * ATT_SCALE + rpb_s[bb + t];
      float pp = __expf(l);            // |l| <= ~1.2 for this data: safe
      den += pp;
      float vv[8];
      unpack8(vw, vv);
      #pragma unroll
      for (int i = 0; i < 8; i++) av[i] = fmaf(pp, vv[i], av[i]);
    }
    kC = kA; vC = vA;
    kA = kB; vA = vB;
  }
  float inv = 1.f / den;

  int pl = wid * 8 + w;
  int cb = head * 8;
  #pragma unroll
  for (int i = 0; i < 8; i++)
    A[pl][cb + i] = av[i] * inv;
  __syncthreads();

  int jb = __builtin_amdgcn_readfirstlane(wid * 8);
  int p0 = bid * 64;
  float acc[8];
  #pragma unroll
  for (int j = 0; j < 8; j++) acc[j] = b_proj[jb + j];
  #pragma unroll 8
  for (int c = 0; c < NC; c++) {
    float a = A[lane][c];
    #pragma unroll
    for (int j = 0; j < 8; j++)
      acc[j] = fmaf(a, w_proj[c*64 + jb + j], acc[j]);
  }
  #pragma unroll
  for (int j = 0; j < 8; j++)
    out[(size_t)(jb + j) * PTOT + p0 + lane] = acc[j];
}

extern "C" void kernel_launch(void* const* d_in, const int* in_sizes, int n_in,
                              void* d_out, int out_size, void* d_ws, size_t ws_size,
                              hipStream_t stream) {
  const float* skip = (const float*)d_in[0];
  const float* up   = (const float*)d_in[1];
  const float* w_qk = (const float*)d_in[2];
  const float* b_qk = (const float*)d_in[3];
  const float* w_v  = (const float*)d_in[4];
  const float* b_v  = (const float*)d_in[5];
  const float* w_pr = (const float*)d_in[6];
  const float* b_pr = (const float*)d_in[7];
  const float* rpb  = (const float*)d_in[8];
  float* ws  = (float*)d_ws;
  float* out = (float*)d_out;

  k_stats<<<128, 1024, 0, stream>>>(skip, up, ws);
  k_qkv<<<512, 256, 0, stream>>>(skip, up, w_qk, b_qk, w_v, b_v, ws);
  k_attn_proj<<<(PD*PH)/8, 512, 0, stream>>>(rpb, w_pr, b_pr, ws, out);
}